// Round 3
// baseline (54.266 us; speedup 1.0000x reference)
//
#include <hip/hip_runtime.h>
#include <math.h>

#define GRID_G 16
#define SPLIT  4            // threads per pair (each does GRID_G/SPLIT gy rows)
#define NTAB   4096         // sigmoid LUT entries (16 KB LDS)

__global__ __launch_bounds__(256) void piou_pairwise_kernel(
    const float* __restrict__ P,   // [N,5] cx,cy,w,h,theta
    const float* __restrict__ T,   // [M,5]
    float* __restrict__ out,       // [N,M]
    int N, int M)
{
    __shared__ float tab[NTAB];

    const float K2    = 10.0f * 1.4426950408889634f; // k * log2(e)
    const float ZCUT  = 25.0f;                       // |z| cut: sig err < 3e-8
    const float SCALE = (float)NTAB / (2.0f * ZCUT);
    const float INVSC = (2.0f * ZCUT) / (float)NTAB;

    // LUT: tab[i] = sigmoid at bin center, S(z) = 1/(1+2^z)
    for (int q = threadIdx.x; q < NTAB; q += 256) {
        float z = ((float)q + 0.5f) * INVSC - ZCUT;
        tab[q] = 1.0f / (1.0f + exp2f(z));
    }
    __syncthreads();

    int gtid = blockIdx.x * blockDim.x + threadIdx.x;
    int pair = gtid >> 2;          // SPLIT = 4
    int sub  = gtid & 3;
    if (pair >= N * M) return;
    int bi = pair / M;
    int bj = pair - bi * M;

    float cxp = P[5*bi+0], cyp = P[5*bi+1], wp = P[5*bi+2], hp = P[5*bi+3], thp = P[5*bi+4];
    float cxt = T[5*bj+0], cyt = T[5*bj+1], wt = T[5*bj+2], ht = T[5*bj+3], tht = T[5*bj+4];

    float sp, cp, st, ct;
    sincosf(thp, &sp, &cp);
    sincosf(tht, &st, &ct);

    // AABBs and joint region
    float acp = fabsf(cp), asp = fabsf(sp);
    float hwp = 0.5f * (wp * acp + hp * asp);
    float hhp = 0.5f * (wp * asp + hp * acp);
    float act = fabsf(ct), ast = fabsf(st);
    float hwt = 0.5f * (wt * act + ht * ast);
    float hht = 0.5f * (wt * ast + ht * act);

    float xmin = fminf(cxp - hwp, cxt - hwt);
    float xmax = fmaxf(cxp + hwp, cxt + hwt);
    float ymin = fminf(cyp - hhp, cyt - hht);
    float ymax = fmaxf(cyp + hhp, cyt + hht);

    float dxr = xmax - xmin;
    float dyr = ymax - ymin;
    const float inv_g = 1.0f / (float)GRID_G;
    float stepx = dxr * inv_g;

    // LUT index:  t = K2S*|rw| + cX   (z mapped to [0, NTAB))
    const float K2S = K2 * SCALE;
    float cW1 = (ZCUT - 0.5f * K2 * wp) * SCALE;
    float cH1 = (ZCUT - 0.5f * K2 * hp) * SCALE;
    float cW2 = (ZCUT - 0.5f * K2 * wt) * SCALE;
    float cH2 = (ZCUT - 0.5f * K2 * ht) * SCALE;

    // per-gx increments of rotated coordinates
    float iw1 = stepx * cp, ih1 = -stepx * sp;
    float iw2 = stepx * ct, ih2 = -stepx * st;

    float px0 = fmaf(dxr, 0.5f * inv_g, xmin);
    float dxp = px0 - cxp, dxt = px0 - cxt;

    const float TMAXF = (float)NTAB - 0.51f;

    float s1 = 0.f, s2 = 0.f, s12 = 0.f;

    #pragma unroll
    for (int r = 0; r < GRID_G / SPLIT; ++r) {
        int gy = sub * (GRID_G / SPLIT) + r;
        float py  = fmaf(dyr, ((float)gy + 0.5f) * inv_g, ymin);
        float dyp = py - cyp, dyt = py - cyt;

        float rw1_0 =  dxp * cp + dyp * sp;
        float rh1_0 = -dxp * sp + dyp * cp;
        float rw2_0 =  dxt * ct + dyt * st;
        float rh2_0 = -dxt * st + dyt * ct;

        #pragma unroll
        for (int gx = 0; gx < GRID_G; ++gx) {
            float g = (float)gx;
            float rw1 = fmaf(g, iw1, rw1_0);
            float rh1 = fmaf(g, ih1, rh1_0);
            float rw2 = fmaf(g, iw2, rw2_0);
            float rh2 = fmaf(g, ih2, rh2_0);

            // v_fma(abs) -> v_med3 -> v_cvt -> ds_read
            float t1w = fminf(fmaxf(fmaf(fabsf(rw1), K2S, cW1), 0.f), TMAXF);
            float t1h = fminf(fmaxf(fmaf(fabsf(rh1), K2S, cH1), 0.f), TMAXF);
            float t2w = fminf(fmaxf(fmaf(fabsf(rw2), K2S, cW2), 0.f), TMAXF);
            float t2h = fminf(fmaxf(fmaf(fabsf(rh2), K2S, cH2), 0.f), TMAXF);

            float S1w = tab[(int)t1w];
            float S1h = tab[(int)t1h];
            float S2w = tab[(int)t2w];
            float S2h = tab[(int)t2h];

            float F1 = S1w * S1h;
            float F2 = S2w * S2h;
            s1 += F1;
            s2 += F2;
            s12 = fmaf(F1, F2, s12);
        }
    }

    // combine SPLIT partial sums (lanes of same pair adjacent)
    #pragma unroll
    for (int m = 1; m < SPLIT; m <<= 1) {
        s1  += __shfl_xor(s1,  m);
        s2  += __shfl_xor(s2,  m);
        s12 += __shfl_xor(s12, m);
    }

    if (sub == 0)
        out[pair] = s12 / (s1 + s2 - s12 + 1e-6f);
}

extern "C" void kernel_launch(void* const* d_in, const int* in_sizes, int n_in,
                              void* d_out, int out_size, void* d_ws, size_t ws_size,
                              hipStream_t stream) {
    const float* P = (const float*)d_in[0];
    const float* T = (const float*)d_in[1];
    float* out = (float*)d_out;

    int N = in_sizes[0] / 5;
    int M = in_sizes[1] / 5;
    long long total = (long long)N * M * SPLIT;
    int block = 256;
    int grid = (int)((total + block - 1) / block);
    piou_pairwise_kernel<<<grid, block, 0, stream>>>(P, T, out, N, M);
}